// Round 14
// baseline (218.877 us; speedup 1.0000x reference)
//
#include <hip/hip_runtime.h>
#include <stdint.h>

// Attention B=2,H=16,S=2048,D=64 fp32. Round 18: occupancy 3->4 blocks/CU by
// REGISTER DIET, keeping the 64-row tile: the loop-invariant Qf fragments
// (32 VGPRs held for the whole kernel) move to LDS and are re-read per
// iteration (8x ds_read_b128, XOR-swizzled, per-nt staggered to cap
// transient pressure). Live set ~148 -> ~116 < 128 => launch_bounds(256,4).
// LDS packs to exactly 40960B (staging 32KB + Q 8KB, epilogue overlays) ->
// 4 blocks/CU at 160KB. Grid 1024 = EXACTLY 4/CU: single packed phase, no
// lone-block tail (r15's correct diagnosis, paid for without halving MFMA
// work), 16 waves/CU latency hiding.
//
// r17 decomposition: prep was never the gap (coalesced prep left total
// unchanged) -- the ~75us residual is harness overhead; and byte-identical
// fa measured 71.9 vs 62.2 on different containers => +-15% cross-container
// noise; judge this round by OccupancyPercent/MfmaUtil and the spill gate.
// Spill ledger: the ONLY non-spilling variant (r15) was register-REDUCING.
//
// Q LDS layout: [64 rows][8 chunks of 16B], row r chunk c stored at c^(r&7)
// -> fragment reads (row=16nt+lq, chunk 4kc+qd) are <=2-way banked; nt
// selects a +2048B immediate offset; kc flips chunk bit 2 (qoffB=qoffA^64B).
// K/V staging, swizzles, loop discipline byte-identical to r10.

typedef _Float16 f16;
typedef __attribute__((ext_vector_type(4))) _Float16 f16x4;
typedef __attribute__((ext_vector_type(8))) _Float16 f16x8;
typedef __attribute__((ext_vector_type(4))) float f32x4;

constexpr int Bc = 2, Hc = 16, Sc = 2048, Dc = 64;
constexpr size_t NE = (size_t)Bc * Hc * Sc * Dc;

__device__ inline void gld_lds16(const f16* g, f16* l) {
  __builtin_amdgcn_global_load_lds(
      (const __attribute__((address_space(1))) unsigned int*)g,
      (__attribute__((address_space(3))) unsigned int*)l, 16, 0, 0);
}

// ---------------- prep v2 (r17, verified): K cvt; V transpose via LDS -----
__global__ __launch_bounds__(256)
void prep(const float* __restrict__ kp, const float* __restrict__ vp,
          const float* __restrict__ temp,
          f16* __restrict__ kh, f16* __restrict__ vt) {
  __shared__ f16 Vl[64 * 66];
  const int tid = threadIdx.x;
  const int bh = blockIdx.x & 31;
  const int st = blockIdx.x >> 5;
  const float ksc = 1.44269504088896340736f / (temp[0] * 8.0f);

  const size_t base = (size_t)bh * Sc * Dc + (size_t)st * 64 * Dc;
  const float* kg = kp + base;
  f16* khg = kh + base;
#pragma unroll
  for (int i = 0; i < 4; ++i) {
    int f = tid + (i << 8);
    f32x4 a = *(const f32x4*)(kg + f * 4);
    *(f16x4*)(khg + f * 4) = (f16x4){(f16)(a.x * ksc), (f16)(a.y * ksc),
                                     (f16)(a.z * ksc), (f16)(a.w * ksc)};
  }
  const float* vg = vp + base;
  const int vcb = tid & 15, vr = tid >> 4;
#pragma unroll
  for (int i = 0; i < 4; ++i) {
    int row = vr + 16 * i;
    f32x4 a = *(const f32x4*)(vg + row * Dc + vcb * 4);
    *(f16x4*)(&Vl[row * 66 + vcb * 4]) =
        (f16x4){(f16)a.x, (f16)a.y, (f16)a.z, (f16)a.w};
  }
  __syncthreads();
  const int sb = tid & 15, db = tid >> 4;
  f16* vtg = vt + (size_t)bh * Dc * Sc + (size_t)st * 64 + 4 * sb;
#pragma unroll
  for (int c = 0; c < 4; ++c) {
    int d = 4 * db + c;
    f16x4 v4 = (f16x4){Vl[(4 * sb + 0) * 66 + d], Vl[(4 * sb + 1) * 66 + d],
                       Vl[(4 * sb + 2) * 66 + d], Vl[(4 * sb + 3) * 66 + d]};
    *(f16x4*)(vtg + (size_t)d * Sc) = v4;
  }
}

// ---------------- fa18: r10 body, Qf in LDS, 4 blocks/CU ------------------
__global__ __launch_bounds__(256, 4)
void fa18(const float* __restrict__ qp, const f16* __restrict__ kh,
          const f16* __restrict__ vt, float* __restrict__ out) {
  // [0,32768): staging (4 waves x [2KB K + 2KB V] x 2 buf)
  // [32768,40960): Q tile f16 [64][8 chunks], chunk-swizzled
  // epilogue overlays: OsA [0,16896), OsB [16896,33792), Lred [33792,34816)
  __shared__ __align__(16) char smem[40960];

  const int tid = threadIdx.x, lane = tid & 63, w = tid >> 6;
  const int lq = lane & 15, qd = lane >> 4;
  const int L = blockIdx.x;
  const int bh = L & 31;                   // blockIdx%8 == bh%8 (XCD-affine)
  const int qt = L >> 5;

  const size_t base = (size_t)bh * Sc * Dc;

  f16* Kw = (f16*)smem + w * 2048;                 // [2][1024]
  f16* Vw = (f16*)(smem + 16384) + w * 2048;       // [2][1024]
  f16* Qs = (f16*)(smem + 32768);                  // [64][64] swizzled

  // ---- staging gather addresses (swizzle on the global side) ----
  const int oct = (lane & 7) ^ ((lane >> 3) & 7);
  const f16* kg0 = kh + base + (size_t)(16 * w + (lane >> 3)) * 64 + oct * 8;
  const f16* kg1 = kg0 + 8 * 64;
  const int vd = lane >> 1;
  const int vc = (lane & 1) ^ ((lane >> 3) & 1);
  const f16* vg0 = vt + (size_t)bh * Dc * Sc + (size_t)vd * Sc + 16 * w + vc * 8;
  const f16* vg1 = vg0 + (size_t)32 * Sc;

  auto stage = [&](int kt, int b) {
    gld_lds16(kg0 + (size_t)kt * 4096, Kw + b * 1024);
    gld_lds16(kg1 + (size_t)kt * 4096, Kw + b * 1024 + 512);
    gld_lds16(vg0 + kt * 64, Vw + b * 1024);
    gld_lds16(vg1 + kt * 64, Vw + b * 1024 + 512);
  };

  // ---- fragment LDS offsets (f16 units, constant per lane) ----
  const int koff0 = lq * 64 + ((qd) ^ (lq & 7)) * 8;
  const int koff1 = lq * 64 + ((4 + qd) ^ (lq & 7)) * 8;
  int voff[4];
#pragma unroll
  for (int dt = 0; dt < 4; ++dt)
    voff[dt] = (16 * dt + lq) * 16 + (((qd >> 1) ^ ((lq >> 2) & 1)) << 3) +
               (qd & 1) * 4;
  // Q fragment offsets: row=16nt+lq (nt via +1024 imm), chunk (4kc+qd)^(lq&7)
  const int qoffA = lq * 64 + ((qd ^ (lq & 7))) * 8;          // kc=0
  const int qoffB = lq * 64 + (((qd ^ (lq & 7)) ^ 4)) * 8;    // kc=1

  // ---- Q tile -> LDS once (coalesced reads, swizzled write) ----
  {
    const float* qg = qp + base + (size_t)qt * 64 * Dc;
    const int qr = tid >> 2;              // row 0..63
    const int qcc = (tid & 3) * 16;       // f16 col base
    const float* p = qg + qr * Dc + qcc;
    f32x4 a0 = *(const f32x4*)(p);
    f32x4 a1 = *(const f32x4*)(p + 4);
    f32x4 a2 = *(const f32x4*)(p + 8);
    f32x4 a3 = *(const f32x4*)(p + 12);
    auto p0 = __builtin_amdgcn_cvt_pkrtz(a0.x, a0.y);
    auto p1 = __builtin_amdgcn_cvt_pkrtz(a0.z, a0.w);
    auto p2 = __builtin_amdgcn_cvt_pkrtz(a1.x, a1.y);
    auto p3 = __builtin_amdgcn_cvt_pkrtz(a1.z, a1.w);
    auto p4 = __builtin_amdgcn_cvt_pkrtz(a2.x, a2.y);
    auto p5 = __builtin_amdgcn_cvt_pkrtz(a2.z, a2.w);
    auto p6 = __builtin_amdgcn_cvt_pkrtz(a3.x, a3.y);
    auto p7 = __builtin_amdgcn_cvt_pkrtz(a3.z, a3.w);
    f16x8 h0, h1;
    ((decltype(p0)*)&h0)[0] = p0; ((decltype(p0)*)&h0)[1] = p1;
    ((decltype(p0)*)&h0)[2] = p2; ((decltype(p0)*)&h0)[3] = p3;
    ((decltype(p0)*)&h1)[0] = p4; ((decltype(p0)*)&h1)[1] = p5;
    ((decltype(p0)*)&h1)[2] = p6; ((decltype(p0)*)&h1)[3] = p7;
    const int c0 = ((qcc >> 3) + 0) ^ (qr & 7);
    const int c1 = ((qcc >> 3) + 1) ^ (qr & 7);
    *(f16x8*)(Qs + qr * 64 + c0 * 8) = h0;
    *(f16x8*)(Qs + qr * 64 + c1 * 8) = h1;
  }
  __syncthreads();              // Q visible to all waves (drains vm/lgkm once)

  // pinned zero accumulator source
  float z0 = 0.f, z1 = 0.f, z2 = 0.f, z3 = 0.f;
  asm volatile("" : "+v"(z0), "+v"(z1), "+v"(z2), "+v"(z3));
  const f32x4 Zc = (f32x4){z0, z1, z2, z3};

  f32x4 Oa[4][4];
  float ls[4];
#pragma unroll
  for (int nt = 0; nt < 4; ++nt) {
    ls[nt] = 0.f;
#pragma unroll
    for (int dt = 0; dt < 4; ++dt) Oa[nt][dt] = (f32x4){0.f, 0.f, 0.f, 0.f};
  }

  stage(0, 0);
  stage(1, 1);

  // Body kt (r10 discipline + per-nt Q reads from LDS):
#define FA_BODY(BUF, WN, STGKT)                                               \
  {                                                                           \
    asm volatile("s_waitcnt vmcnt(" WN ")" ::: "memory");                     \
    const f16* KB = Kw + (BUF) * 1024;                                        \
    const f16* VB = Vw + (BUF) * 1024;                                        \
    f16x8 K0 = *(const f16x8*)(KB + koff0);                                   \
    f16x8 K1 = *(const f16x8*)(KB + koff1);                                   \
    f16x4 Vf[4];                                                              \
    _Pragma("unroll")                                                         \
    for (int dt = 0; dt < 4; ++dt) Vf[dt] = *(const f16x4*)(VB + voff[dt]);   \
    asm volatile("s_waitcnt lgkmcnt(0)" ::: "memory");                        \
    if ((STGKT) < 32) stage((STGKT), (BUF));                                  \
    f32x4 St[4];                                                              \
    _Pragma("unroll")                                                         \
    for (int nt = 0; nt < 4; ++nt) {                                          \
      f16x8 q0 = *(const f16x8*)(Qs + qoffA + 1024 * nt);                     \
      f16x8 q1 = *(const f16x8*)(Qs + qoffB + 1024 * nt);                     \
      f32x4 a = __builtin_amdgcn_mfma_f32_16x16x32_f16(K0, q0, Zc, 0, 0, 0);  \
      a = __builtin_amdgcn_mfma_f32_16x16x32_f16(K1, q1, a, 0, 0, 0);         \
      St[nt] = a;                                                             \
    }                                                                         \
    f16x4 Pf[4];                                                              \
    _Pragma("unroll")                                                         \
    for (int nt = 0; nt < 4; ++nt) {                                          \
      float e0 = __builtin_amdgcn_exp2f(St[nt].x);                            \
      float e1 = __builtin_amdgcn_exp2f(St[nt].y);                            \
      float e2 = __builtin_amdgcn_exp2f(St[nt].z);                            \
      float e3 = __builtin_amdgcn_exp2f(St[nt].w);                            \
      ls[nt] += (e0 + e1) + (e2 + e3);                                        \
      auto lo = __builtin_amdgcn_cvt_pkrtz(e0, e1);                           \
      auto hi = __builtin_amdgcn_cvt_pkrtz(e2, e3);                           \
      f16x4 p;                                                                \
      ((decltype(lo)*)&p)[0] = lo;                                            \
      ((decltype(lo)*)&p)[1] = hi;                                            \
      Pf[nt] = p;                                                             \
    }                                                                         \
    _Pragma("unroll")                                                         \
    for (int nt = 0; nt < 4; ++nt)                                            \
      _Pragma("unroll")                                                       \
      for (int dt = 0; dt < 4; ++dt)                                          \
        Oa[nt][dt] = __builtin_amdgcn_mfma_f32_16x16x16f16(Pf[nt], Vf[dt],    \
                                                           Oa[nt][dt], 0, 0, 0); \
  }

#pragma unroll 1
  for (int kt2 = 0; kt2 < 15; ++kt2) {
    FA_BODY(0, "4", 2 * kt2 + 2)
    FA_BODY(1, "4", 2 * kt2 + 3)
  }
  FA_BODY(0, "4", 32)   // kt=30
  FA_BODY(1, "0", 32)   // kt=31, drain

#undef FA_BODY

  // ---- epilogue: row sums + O tree-reduction (LDS reused) ----
#pragma unroll
  for (int nt = 0; nt < 4; ++nt) {
    float l = ls[nt];
    l += __shfl_xor(l, 16, 64);
    l += __shfl_xor(l, 32, 64);
    ls[nt] = l;
  }
  __syncthreads();              // all waves done with staging + Q LDS
  float* Lr = (float*)(smem + 33792);          // [4][64]
  if (qd == 0) {
#pragma unroll
    for (int nt = 0; nt < 4; ++nt) Lr[w * 64 + 16 * nt + lq] = ls[nt];
  }
  float* OsA = (float*)smem;
  float* OsB = (float*)(smem + 16896);
  float* Os = (w & 2) ? OsB : OsA;
  if (!(w & 1)) {
#pragma unroll
    for (int nt = 0; nt < 4; ++nt)
#pragma unroll
      for (int dt = 0; dt < 4; ++dt)
#pragma unroll
        for (int r = 0; r < 4; ++r)
          Os[(16 * nt + 4 * qd + r) * 66 + 16 * dt + lq] = Oa[nt][dt][r];
  }
  __syncthreads();
  if (w & 1) {
#pragma unroll
    for (int nt = 0; nt < 4; ++nt)
#pragma unroll
      for (int dt = 0; dt < 4; ++dt)
#pragma unroll
        for (int r = 0; r < 4; ++r)
          Os[(16 * nt + 4 * qd + r) * 66 + 16 * dt + lq] += Oa[nt][dt][r];
  }
  __syncthreads();

  float* og = out + base + (size_t)qt * 64 * Dc;
#pragma unroll
  for (int r = 0; r < 16; ++r) {
    int row = 16 * w + r;
    float l = Lr[0 * 64 + row] + Lr[1 * 64 + row] + Lr[2 * 64 + row] +
              Lr[3 * 64 + row];
    float vo = OsA[row * 66 + lane] + OsB[row * 66 + lane];
    og[(size_t)row * Dc + lane] = vo / l;
  }
}

extern "C" void kernel_launch(void* const* d_in, const int* in_sizes, int n_in,
                              void* d_out, int out_size, void* d_ws, size_t ws_size,
                              hipStream_t stream) {
  const float* q    = (const float*)d_in[0];
  const float* k    = (const float*)d_in[1];
  const float* v    = (const float*)d_in[2];
  const float* temp = (const float*)d_in[3];
  float* out = (float*)d_out;

  f16* kh = (f16*)d_ws;          // 8.4 MB
  f16* vt = kh + NE;             // 8.4 MB

  prep<<<dim3(Bc * Hc * (Sc / 64)), dim3(256), 0, stream>>>(k, v, temp, kh, vt);
  fa18<<<dim3(Bc * Hc * (Sc / 64)), dim3(256), 0, stream>>>(q, kh, vt, out);
}